// Round 13
// baseline (273.026 us; speedup 1.0000x reference)
//
#include <hip/hip_runtime.h>
#include <hip/hip_bf16.h>
#include <math.h>

#define IN_DIM 256
#define HIDDEN 256
#define HEADS 8
#define FPH 32
#define NCLS 40

typedef __attribute__((ext_vector_type(8))) short bf16x8;
typedef __attribute__((ext_vector_type(4))) float f32x4;

__device__ inline unsigned short f2bf(float f) {
    unsigned int u = __float_as_uint(f);
    unsigned int r = (u + 0x7FFF + ((u >> 16) & 1)) >> 16;
    return (unsigned short)r;
}
__device__ inline float bf2f(unsigned short u) {
    return __uint_as_float(((unsigned int)u) << 16);
}

// ---------------- stage1: hist (blocks < nhist) || prep (blocks >= nhist) ----------------
// prep blocks: 0-255 -> W1tb col-major + Aw1 (segmented shfl reduce);
//              256-319 -> W2tb[64][256]: rows 0-39 transpose, 48/49 = W2@a_src2 / W2@a_dst2, rest 0.
__global__ __launch_bounds__(256) void stage1_kernel(const int* __restrict__ dst, int* __restrict__ deg, int E,
                                                     const float* __restrict__ W1, const float* __restrict__ W2,
                                                     const float* __restrict__ a_src1, const float* __restrict__ a_dst1,
                                                     const float* __restrict__ a_src2, const float* __restrict__ a_dst2,
                                                     unsigned short* __restrict__ W1tb,
                                                     unsigned short* __restrict__ W2tb,
                                                     unsigned short* __restrict__ Aw, int nhist) {
    int bid = blockIdx.x;
    int tid = threadIdx.x;
    if (bid < nhist) {
        int e = bid * 256 + tid;
        if (e < E) atomicAdd(&deg[dst[e]], 1);
        return;
    }
    int pbid = bid - nhist;
    if (pbid < 256) {
        int k = pbid, j = tid;
        float w = W1[(size_t)k * 256 + j];
        W1tb[(size_t)j * 256 + k] = f2bf(w);
        float s = w * a_src1[j];
        float d = w * a_dst1[j];
#pragma unroll
        for (int m = 1; m < 32; m <<= 1) {
            s += __shfl_xor(s, m, 64);
            d += __shfl_xor(d, m, 64);
        }
        if ((j & 31) == 0) {
            int hd = j >> 5;
            Aw[(size_t)(2 * hd) * 256 + k]     = f2bf(s);
            Aw[(size_t)(2 * hd + 1) * 256 + k] = f2bf(d);
        }
    } else {
        int c = pbid - 256;  // 0..63
        if (c < NCLS) {
            W2tb[(size_t)c * 256 + tid] = f2bf(W2[(size_t)tid * NCLS + c]);
        } else if (c == 48 || c == 49) {
            const float* aptr = (c == 48) ? a_src2 : a_dst2;
            const float* wr = &W2[(size_t)tid * NCLS];
            float s = 0.f;
#pragma unroll
            for (int f = 0; f < NCLS; f++) s += wr[f] * aptr[f];
            W2tb[(size_t)c * 256 + tid] = f2bf(s);
        } else {
            W2tb[(size_t)c * 256 + tid] = 0;
        }
    }
}

__global__ __launch_bounds__(1024) void scan_blocks_kernel(const int* __restrict__ deg,
                                                           int* __restrict__ excl,
                                                           int* __restrict__ bsum, int N) {
    __shared__ int sm[1024];
    int t = threadIdx.x;
    int g = blockIdx.x * 1024 + t;
    int v = (g < N) ? deg[g] : 0;
    sm[t] = v;
    __syncthreads();
    for (int o = 1; o < 1024; o <<= 1) {
        int add = (t >= o) ? sm[t - o] : 0;
        __syncthreads();
        sm[t] += add;
        __syncthreads();
    }
    if (g < N) excl[g] = sm[t] - v;
    if (t == 1023) bsum[blockIdx.x] = sm[1023];
}

__global__ void add_base_kernel(const int* __restrict__ excl, const int* __restrict__ bsum,
                                int* __restrict__ offs, int* __restrict__ cursor, int N, int nb) {
    int g = blockIdx.x * blockDim.x + threadIdx.x;
    if (g > N) return;
    int nblk = g >> 10;
    int lim = (g == N) ? nb : nblk;
    int base = 0;
    for (int i = 0; i < lim; i++) base += bsum[i];
    if (g < N) {
        int o = excl[g] + base;
        offs[g] = o;
        cursor[g] = o;
    } else {
        offs[N] = base;
    }
}

// ---------------- stage2: fill (blocks < nfill) || gemm1+alpha1 (blocks >= nfill) ----------------
__global__ __launch_bounds__(256) void stage2_kernel(const int* __restrict__ src, const int* __restrict__ dst,
                                                     int* __restrict__ cursor, int* __restrict__ adjsrc, int E,
                                                     const float* __restrict__ A,
                                                     const unsigned short* __restrict__ Btb,
                                                     const unsigned short* __restrict__ Aw,
                                                     unsigned short* __restrict__ Cb,
                                                     float* __restrict__ as_o,
                                                     float* __restrict__ ad_o, int M, int nfill) {
    __shared__ unsigned short smem[64 * 264];  // 16896 >= 13440 (K-loop), == epilogue Co
    int bid = blockIdx.x;
    int t = threadIdx.x;
    if (bid < nfill) {
        int e = bid * 256 + t;
        if (e < E) {
            int d = dst[e];
            int pos = atomicAdd(&cursor[d], 1);
            adjsrc[pos] = src[e];
        }
        return;
    }
    int gbid = bid - nfill;
    unsigned short* As = smem;
    unsigned short* Bs = smem + 64 * 40;
    unsigned short* Bsa = smem + 64 * 40 + 256 * 40;
    int wave = t >> 6, lane = t & 63;
    int rowBase = gbid * 64;
    int lrow = lane & 15, lk = (lane >> 4) * 8;
    f32x4 acc[16] = {};
    f32x4 acca = {};
    int arow = t >> 2, akq = (t & 3) * 8;
    for (int k0 = 0; k0 < 256; k0 += 32) {
        int grow = rowBase + arow;
        float4 a0 = {0.f, 0.f, 0.f, 0.f}, a1 = {0.f, 0.f, 0.f, 0.f};
        if (grow < M) {
            a0 = *reinterpret_cast<const float4*>(&A[(size_t)grow * 256 + k0 + akq]);
            a1 = *reinterpret_cast<const float4*>(&A[(size_t)grow * 256 + k0 + akq + 4]);
        }
        ushort4 p0 = {f2bf(a0.x), f2bf(a0.y), f2bf(a0.z), f2bf(a0.w)};
        ushort4 p1 = {f2bf(a1.x), f2bf(a1.y), f2bf(a1.z), f2bf(a1.w)};
        *reinterpret_cast<ushort4*>(&As[arow * 40 + akq]) = p0;
        *reinterpret_cast<ushort4*>(&As[arow * 40 + akq + 4]) = p1;
#pragma unroll
        for (int q = 0; q < 4; q++) {
            uint4 bv = *reinterpret_cast<const uint4*>(&Btb[(size_t)t * 256 + k0 + q * 8]);
            *reinterpret_cast<uint4*>(&Bs[t * 40 + q * 8]) = bv;
        }
        if (t < 16) {
#pragma unroll
            for (int q = 0; q < 4; q++) {
                uint4 av = *reinterpret_cast<const uint4*>(&Aw[(size_t)t * 256 + k0 + q * 8]);
                *reinterpret_cast<uint4*>(&Bsa[t * 40 + q * 8]) = av;
            }
        }
        __syncthreads();
        bf16x8 a = *reinterpret_cast<const bf16x8*>(&As[(wave * 16 + lrow) * 40 + lk]);
#pragma unroll
        for (int j = 0; j < 16; j++) {
            bf16x8 b = *reinterpret_cast<const bf16x8*>(&Bs[(j * 16 + lrow) * 40 + lk]);
            acc[j] = __builtin_amdgcn_mfma_f32_16x16x32_bf16(a, b, acc[j], 0, 0, 0);
        }
        bf16x8 ba = *reinterpret_cast<const bf16x8*>(&Bsa[lrow * 40 + lk]);
        acca = __builtin_amdgcn_mfma_f32_16x16x32_bf16(a, ba, acca, 0, 0, 0);
        __syncthreads();
    }
    int r0 = (lane >> 4) * 4;
    {
        int c = lrow, hd = c >> 1;
        float* dsts = (c & 1) ? ad_o : as_o;
#pragma unroll
        for (int r = 0; r < 4; r++) {
            int row = rowBase + wave * 16 + r0 + r;
            if (row < M) dsts[row * HEADS + hd] = acca[r];
        }
    }
    __syncthreads();
    unsigned short* Co = smem;  // [64][264]
#pragma unroll
    for (int j = 0; j < 16; j++)
#pragma unroll
        for (int r = 0; r < 4; r++)
            Co[(wave * 16 + r0 + r) * 264 + j * 16 + lrow] = f2bf(acc[j][r]);
    __syncthreads();
    int wrow = t >> 2, wchunk = (t & 3) * 64;
    int growW = rowBase + wrow;
    if (growW < M) {
#pragma unroll
        for (int q = 0; q < 8; q++) {
            uint4 v = *reinterpret_cast<const uint4*>(&Co[wrow * 264 + wchunk + q * 8]);
            *reinterpret_cast<uint4*>(&Cb[(size_t)growW * 256 + wchunk + q * 8]) = v;
        }
    }
}

// ---------------- GEMM2 MFMA + fused alpha2: out1b [M,256] x W2tb[64,256] -> h2b [M,48], as2/ad2 ----------------
__global__ __launch_bounds__(256) void gemm2_mfma(const unsigned short* __restrict__ Ab,
                                                  const unsigned short* __restrict__ Btb,
                                                  unsigned short* __restrict__ Cb,
                                                  float* __restrict__ as_o,
                                                  float* __restrict__ ad_o, int M) {
    __shared__ unsigned short As[64 * 40];
    __shared__ unsigned short Bs[64 * 40];
    int t = threadIdx.x;
    int wave = t >> 6, lane = t & 63;
    int rowBase = blockIdx.x * 64;
    int lrow = lane & 15, lk = (lane >> 4) * 8;
    f32x4 acc[4] = {};
    int srow = t >> 2, skq = (t & 3) * 8;
    for (int k0 = 0; k0 < 256; k0 += 32) {
        uint4 av = {0, 0, 0, 0};
        int grow = rowBase + srow;
        if (grow < M) av = *reinterpret_cast<const uint4*>(&Ab[(size_t)grow * 256 + k0 + skq]);
        *reinterpret_cast<uint4*>(&As[srow * 40 + skq]) = av;
        uint4 bv = *reinterpret_cast<const uint4*>(&Btb[(size_t)srow * 256 + k0 + skq]);
        *reinterpret_cast<uint4*>(&Bs[srow * 40 + skq]) = bv;
        __syncthreads();
        bf16x8 a = *reinterpret_cast<const bf16x8*>(&As[(wave * 16 + lrow) * 40 + lk]);
#pragma unroll
        for (int j = 0; j < 4; j++) {
            bf16x8 b = *reinterpret_cast<const bf16x8*>(&Bs[(j * 16 + lrow) * 40 + lk]);
            acc[j] = __builtin_amdgcn_mfma_f32_16x16x32_bf16(a, b, acc[j], 0, 0, 0);
        }
        __syncthreads();
    }
    int crow0 = rowBase + wave * 16 + (lane >> 4) * 4;
    int ccol = lane & 15;
#pragma unroll
    for (int j = 0; j < 3; j++)
#pragma unroll
        for (int r = 0; r < 4; r++) {
            int row = crow0 + r;
            if (row < M) Cb[(size_t)row * 48 + j * 16 + ccol] = f2bf(acc[j][r]);
        }
    // alpha2: B cols 48 (a_src2) and 49 (a_dst2)
    if (ccol < 2) {
        float* dsts = ccol ? ad_o : as_o;
#pragma unroll
        for (int r = 0; r < 4; r++) {
            int row = crow0 + r;
            if (row < M) dsts[row] = acc[3][r];
        }
    }
}

// ---------------- aggregation layer 1: one wave per node, 8-deep pipelined gather ----------------
__global__ __launch_bounds__(256) void agg1_kernel(const unsigned short* __restrict__ h1b,
                                                   const float* __restrict__ as,
                                                   const float* __restrict__ ad,
                                                   const int* __restrict__ offs,
                                                   const int* __restrict__ adjsrc,
                                                   const float* __restrict__ b,
                                                   unsigned short* __restrict__ outb, int N) {
    int wid = (blockIdx.x * blockDim.x + threadIdx.x) >> 6;
    int lane = threadIdx.x & 63;
    if (wid >= N) return;
    int n = wid;
    int hd = lane >> 3;
    int beg = offs[n], end = offs[n + 1];
    float adh = ad[n * HEADS + hd];
    float ssum = 0.f;
    float4 acc = {0.f, 0.f, 0.f, 0.f};
    int i = beg;
    for (; i + 8 <= end; i += 8) {
        int sidx[8];
        float av[8];
        ushort4 hv[8];
#pragma unroll
        for (int u = 0; u < 8; u++) sidx[u] = adjsrc[i + u];
#pragma unroll
        for (int u = 0; u < 8; u++) av[u] = as[sidx[u] * HEADS + hd];
#pragma unroll
        for (int u = 0; u < 8; u++)
            hv[u] = *reinterpret_cast<const ushort4*>(&h1b[(size_t)sidx[u] * HIDDEN + lane * 4]);
#pragma unroll
        for (int u = 0; u < 8; u++) {
            float e = av[u] + adh;
            e = e > 0.f ? e : 0.2f * e;
            float ex = __expf(e);
            ssum += ex;
            acc.x += ex * bf2f(hv[u].x);
            acc.y += ex * bf2f(hv[u].y);
            acc.z += ex * bf2f(hv[u].z);
            acc.w += ex * bf2f(hv[u].w);
        }
    }
    for (; i + 4 <= end; i += 4) {
        int sidx[4];
        float av[4];
        ushort4 hv[4];
#pragma unroll
        for (int u = 0; u < 4; u++) sidx[u] = adjsrc[i + u];
#pragma unroll
        for (int u = 0; u < 4; u++) av[u] = as[sidx[u] * HEADS + hd];
#pragma unroll
        for (int u = 0; u < 4; u++)
            hv[u] = *reinterpret_cast<const ushort4*>(&h1b[(size_t)sidx[u] * HIDDEN + lane * 4]);
#pragma unroll
        for (int u = 0; u < 4; u++) {
            float e = av[u] + adh;
            e = e > 0.f ? e : 0.2f * e;
            float ex = __expf(e);
            ssum += ex;
            acc.x += ex * bf2f(hv[u].x);
            acc.y += ex * bf2f(hv[u].y);
            acc.z += ex * bf2f(hv[u].z);
            acc.w += ex * bf2f(hv[u].w);
        }
    }
    for (; i < end; i++) {
        int s = adjsrc[i];
        float e = as[s * HEADS + hd] + adh;
        e = e > 0.f ? e : 0.2f * e;
        float ex = __expf(e);
        ssum += ex;
        ushort4 hv = *reinterpret_cast<const ushort4*>(&h1b[(size_t)s * HIDDEN + lane * 4]);
        acc.x += ex * bf2f(hv.x);
        acc.y += ex * bf2f(hv.y);
        acc.z += ex * bf2f(hv.z);
        acc.w += ex * bf2f(hv.w);
    }
    float inv = 1.f / (ssum + 1e-16f);
    int col = lane * 4;
    float4 o;
    o.x = acc.x * inv + b[col + 0];
    o.y = acc.y * inv + b[col + 1];
    o.z = acc.z * inv + b[col + 2];
    o.w = acc.w * inv + b[col + 3];
    o.x = o.x > 0.f ? o.x : expm1f(o.x);
    o.y = o.y > 0.f ? o.y : expm1f(o.y);
    o.z = o.z > 0.f ? o.z : expm1f(o.z);
    o.w = o.w > 0.f ? o.w : expm1f(o.w);
    ushort4 ob;
    ob.x = f2bf(o.x); ob.y = f2bf(o.y); ob.z = f2bf(o.z); ob.w = f2bf(o.w);
    *reinterpret_cast<ushort4*>(&outb[(size_t)n * HIDDEN + col]) = ob;
}

// ---------------- aggregation layer 2: 4-deep pipelined ----------------
__global__ __launch_bounds__(256) void agg2_kernel(const unsigned short* __restrict__ h2b,
                                                   const float* __restrict__ as,
                                                   const float* __restrict__ ad,
                                                   const int* __restrict__ offs,
                                                   const int* __restrict__ adjsrc,
                                                   const float* __restrict__ b,
                                                   float* __restrict__ out, int N) {
    int wid = (blockIdx.x * blockDim.x + threadIdx.x) >> 6;
    int lane = threadIdx.x & 63;
    if (wid >= N) return;
    int n = wid;
    int beg = offs[n], end = offs[n + 1];
    float adh = ad[n];
    float ssum = 0.f;
    float acc = 0.f;
    bool act = lane < NCLS;
    int i = beg;
    for (; i + 4 <= end; i += 4) {
        int s0 = adjsrc[i + 0];
        int s1 = adjsrc[i + 1];
        int s2 = adjsrc[i + 2];
        int s3 = adjsrc[i + 3];
        float a0 = as[s0];
        float a1 = as[s1];
        float a2 = as[s2];
        float a3 = as[s3];
        float h0 = 0.f, h1 = 0.f, h2 = 0.f, h3 = 0.f;
        if (act) {
            h0 = bf2f(h2b[(size_t)s0 * 48 + lane]);
            h1 = bf2f(h2b[(size_t)s1 * 48 + lane]);
            h2 = bf2f(h2b[(size_t)s2 * 48 + lane]);
            h3 = bf2f(h2b[(size_t)s3 * 48 + lane]);
        }
        float e0 = a0 + adh; e0 = e0 > 0.f ? e0 : 0.2f * e0; float x0 = __expf(e0);
        float e1 = a1 + adh; e1 = e1 > 0.f ? e1 : 0.2f * e1; float x1 = __expf(e1);
        float e2 = a2 + adh; e2 = e2 > 0.f ? e2 : 0.2f * e2; float x2 = __expf(e2);
        float e3 = a3 + adh; e3 = e3 > 0.f ? e3 : 0.2f * e3; float x3 = __expf(e3);
        ssum += (x0 + x1) + (x2 + x3);
        acc += x0 * h0 + x1 * h1 + x2 * h2 + x3 * h3;
    }
    for (; i < end; i++) {
        int s = adjsrc[i];
        float e = as[s] + adh;
        e = e > 0.f ? e : 0.2f * e;
        float ex = __expf(e);
        ssum += ex;
        if (act) acc += ex * bf2f(h2b[(size_t)s * 48 + lane]);
    }
    if (act) {
        float inv = 1.f / (ssum + 1e-16f);
        out[(size_t)n * NCLS + lane] = acc * inv + b[lane];
    }
}

extern "C" void kernel_launch(void* const* d_in, const int* in_sizes, int n_in,
                              void* d_out, int out_size, void* d_ws, size_t ws_size,
                              hipStream_t stream) {
    const float* x      = (const float*)d_in[0];
    const int*   ei     = (const int*)d_in[1];
    const float* W1     = (const float*)d_in[2];
    const float* a_src1 = (const float*)d_in[3];
    const float* a_dst1 = (const float*)d_in[4];
    const float* b1     = (const float*)d_in[5];
    const float* W2     = (const float*)d_in[6];
    const float* a_src2 = (const float*)d_in[7];
    const float* a_dst2 = (const float*)d_in[8];
    const float* b2     = (const float*)d_in[9];
    float* out = (float*)d_out;

    const int N = in_sizes[0] / IN_DIM;
    const int E = in_sizes[1] / 2;
    const int* src = ei;
    const int* dst = ei + E;

    char* ws = (char*)d_ws;
    size_t off = 0;
    auto alloc = [&](size_t bytes) {
        void* p = ws + off;
        off = (off + bytes + 255) & ~(size_t)255;
        return p;
    };
    int*   deg    = (int*)alloc((size_t)N * 4);
    int*   excl   = (int*)alloc((size_t)N * 4);
    int*   bsum   = (int*)alloc((size_t)256 * 4);
    int*   cursor = (int*)alloc((size_t)N * 4);
    int*   offs   = (int*)alloc((size_t)(N + 1) * 4);
    int*   adjsrc = (int*)alloc((size_t)E * 4);
    unsigned short* W1tb  = (unsigned short*)alloc((size_t)256 * 256 * 2);
    unsigned short* W2tb  = (unsigned short*)alloc((size_t)64 * 256 * 2);
    unsigned short* Aw    = (unsigned short*)alloc((size_t)16 * 256 * 2);
    unsigned short* h1b   = (unsigned short*)alloc((size_t)N * HIDDEN * 2);
    unsigned short* out1b = (unsigned short*)alloc((size_t)N * HIDDEN * 2);
    unsigned short* h2b   = (unsigned short*)alloc((size_t)N * 48 * 2);
    float* as1    = (float*)alloc((size_t)N * HEADS * 4);
    float* ad1    = (float*)alloc((size_t)N * HEADS * 4);
    float* as2    = (float*)alloc((size_t)N * 4);
    float* ad2    = (float*)alloc((size_t)N * 4);

    const int nb = (N + 1023) / 1024;
    const int nhist = (E + 255) / 256;
    const int nfill = (E + 255) / 256;
    const int ng1 = (N + 63) / 64;

    hipMemsetAsync(deg, 0, (size_t)N * 4, stream);
    stage1_kernel<<<dim3(nhist + 320), dim3(256), 0, stream>>>(dst, deg, E, W1, W2, a_src1, a_dst1,
                                                               a_src2, a_dst2, W1tb, W2tb, Aw, nhist);
    scan_blocks_kernel<<<dim3(nb), dim3(1024), 0, stream>>>(deg, excl, bsum, N);
    add_base_kernel<<<dim3((N + 256) / 256), dim3(256), 0, stream>>>(excl, bsum, offs, cursor, N, nb);
    stage2_kernel<<<dim3(nfill + ng1), dim3(256), 0, stream>>>(src, dst, cursor, adjsrc, E,
                                                               x, W1tb, Aw, h1b, as1, ad1, N, nfill);
    agg1_kernel<<<dim3((N + 3) / 4), dim3(256), 0, stream>>>(h1b, as1, ad1, offs, adjsrc, b1, out1b, N);

    gemm2_mfma<<<dim3(ng1), dim3(256), 0, stream>>>(out1b, W2tb, h2b, as2, ad2, N);
    agg2_kernel<<<dim3((N + 3) / 4), dim3(256), 0, stream>>>(h2b, as2, ad2, offs, adjsrc, b2, out, N);
}

// Round 14
// 251.975 us; speedup vs baseline: 1.0835x; 1.0835x over previous
//
#include <hip/hip_runtime.h>
#include <hip/hip_bf16.h>
#include <math.h>

#define IN_DIM 256
#define HIDDEN 256
#define HEADS 8
#define FPH 32
#define NCLS 40

typedef __attribute__((ext_vector_type(8))) short bf16x8;
typedef __attribute__((ext_vector_type(4))) float f32x4;

__device__ inline unsigned short f2bf(float f) {
    unsigned int u = __float_as_uint(f);
    unsigned int r = (u + 0x7FFF + ((u >> 16) & 1)) >> 16;
    return (unsigned short)r;
}
__device__ inline float bf2f(unsigned short u) {
    return __uint_as_float(((unsigned int)u) << 16);
}

// ---------------- CSR build ----------------
__global__ void hist_kernel(const int* __restrict__ dst, int* __restrict__ deg, int E) {
    int e = blockIdx.x * blockDim.x + threadIdx.x;
    if (e < E) atomicAdd(&deg[dst[e]], 1);
}

__global__ __launch_bounds__(1024) void scan_blocks_kernel(const int* __restrict__ deg,
                                                           int* __restrict__ excl,
                                                           int* __restrict__ bsum, int N) {
    __shared__ int sm[1024];
    int t = threadIdx.x;
    int g = blockIdx.x * 1024 + t;
    int v = (g < N) ? deg[g] : 0;
    sm[t] = v;
    __syncthreads();
    for (int o = 1; o < 1024; o <<= 1) {
        int add = (t >= o) ? sm[t - o] : 0;
        __syncthreads();
        sm[t] += add;
        __syncthreads();
    }
    if (g < N) excl[g] = sm[t] - v;
    if (t == 1023) bsum[blockIdx.x] = sm[1023];
}

__global__ void add_base_kernel(const int* __restrict__ excl, const int* __restrict__ bsum,
                                int* __restrict__ offs, int* __restrict__ cursor, int N, int nb) {
    int g = blockIdx.x * blockDim.x + threadIdx.x;
    if (g > N) return;
    int nblk = g >> 10;
    int lim = (g == N) ? nb : nblk;
    int base = 0;
    for (int i = 0; i < lim; i++) base += bsum[i];
    if (g < N) {
        int o = excl[g] + base;
        offs[g] = o;
        cursor[g] = o;
    } else {
        offs[N] = base;
    }
}

__global__ void fill_kernel(const int* __restrict__ src, const int* __restrict__ dst,
                            int* __restrict__ cursor, int* __restrict__ adjsrc, int E) {
    int e = blockIdx.x * blockDim.x + threadIdx.x;
    if (e < E) {
        int d = dst[e];
        int pos = atomicAdd(&cursor[d], 1);
        adjsrc[pos] = src[e];
    }
}

// ---------------- prep: W1^T + Aw1 (coalesced shfl reduce), W2tb[64][256] w/ alpha2 cols ----------------
// grid = 256 + 64 blocks x 256 threads
__global__ void prep_kernel(const float* __restrict__ W1, const float* __restrict__ W2,
                            const float* __restrict__ a_src1, const float* __restrict__ a_dst1,
                            const float* __restrict__ a_src2, const float* __restrict__ a_dst2,
                            unsigned short* __restrict__ W1tb, unsigned short* __restrict__ W2tb,
                            unsigned short* __restrict__ Aw) {
    int bid = blockIdx.x;
    int tid = threadIdx.x;
    if (bid < 256) {
        int k = bid, j = tid;
        float w = W1[(size_t)k * 256 + j];
        W1tb[(size_t)j * 256 + k] = f2bf(w);
        float s = w * a_src1[j];
        float d = w * a_dst1[j];
#pragma unroll
        for (int m = 1; m < 32; m <<= 1) {
            s += __shfl_xor(s, m, 64);
            d += __shfl_xor(d, m, 64);
        }
        if ((j & 31) == 0) {
            int hd = j >> 5;
            Aw[(size_t)(2 * hd) * 256 + k]     = f2bf(s);
            Aw[(size_t)(2 * hd + 1) * 256 + k] = f2bf(d);
        }
    } else {
        int c = bid - 256;  // 0..63
        if (c < NCLS) {
            W2tb[(size_t)c * 256 + tid] = f2bf(W2[(size_t)tid * NCLS + c]);
        } else if (c == 48 || c == 49) {
            // alpha2 is linear in h2: h2.a2 = out1.(W2@a2)
            const float* aptr = (c == 48) ? a_src2 : a_dst2;
            const float* wr = &W2[(size_t)tid * NCLS];
            float s = 0.f;
#pragma unroll
            for (int f = 0; f < NCLS; f++) s += wr[f] * aptr[f];
            W2tb[(size_t)c * 256 + tid] = f2bf(s);
        } else {
            W2tb[(size_t)c * 256 + tid] = 0;
        }
    }
}

// ---------------- GEMM1 MFMA + fused alpha1 (exact: alpha = x . Aw_eff) ----------------
__global__ __launch_bounds__(256) void gemm1_mfma(const float* __restrict__ A,
                                                  const unsigned short* __restrict__ Btb,
                                                  const unsigned short* __restrict__ Aw,
                                                  unsigned short* __restrict__ Cb,
                                                  float* __restrict__ as_o,
                                                  float* __restrict__ ad_o, int M) {
    __shared__ unsigned short smem[64 * 264];  // 16896 >= 13440
    unsigned short* As = smem;
    unsigned short* Bs = smem + 64 * 40;
    unsigned short* Bsa = smem + 64 * 40 + 256 * 40;
    int t = threadIdx.x;
    int wave = t >> 6, lane = t & 63;
    int rowBase = blockIdx.x * 64;
    int lrow = lane & 15, lk = (lane >> 4) * 8;
    f32x4 acc[16] = {};
    f32x4 acca = {};
    int arow = t >> 2, akq = (t & 3) * 8;
    for (int k0 = 0; k0 < 256; k0 += 32) {
        int grow = rowBase + arow;
        float4 a0 = {0.f, 0.f, 0.f, 0.f}, a1 = {0.f, 0.f, 0.f, 0.f};
        if (grow < M) {
            a0 = *reinterpret_cast<const float4*>(&A[(size_t)grow * 256 + k0 + akq]);
            a1 = *reinterpret_cast<const float4*>(&A[(size_t)grow * 256 + k0 + akq + 4]);
        }
        ushort4 p0 = {f2bf(a0.x), f2bf(a0.y), f2bf(a0.z), f2bf(a0.w)};
        ushort4 p1 = {f2bf(a1.x), f2bf(a1.y), f2bf(a1.z), f2bf(a1.w)};
        *reinterpret_cast<ushort4*>(&As[arow * 40 + akq]) = p0;
        *reinterpret_cast<ushort4*>(&As[arow * 40 + akq + 4]) = p1;
#pragma unroll
        for (int q = 0; q < 4; q++) {
            uint4 bv = *reinterpret_cast<const uint4*>(&Btb[(size_t)t * 256 + k0 + q * 8]);
            *reinterpret_cast<uint4*>(&Bs[t * 40 + q * 8]) = bv;
        }
        if (t < 16) {
#pragma unroll
            for (int q = 0; q < 4; q++) {
                uint4 av = *reinterpret_cast<const uint4*>(&Aw[(size_t)t * 256 + k0 + q * 8]);
                *reinterpret_cast<uint4*>(&Bsa[t * 40 + q * 8]) = av;
            }
        }
        __syncthreads();
        bf16x8 a = *reinterpret_cast<const bf16x8*>(&As[(wave * 16 + lrow) * 40 + lk]);
#pragma unroll
        for (int j = 0; j < 16; j++) {
            bf16x8 b = *reinterpret_cast<const bf16x8*>(&Bs[(j * 16 + lrow) * 40 + lk]);
            acc[j] = __builtin_amdgcn_mfma_f32_16x16x32_bf16(a, b, acc[j], 0, 0, 0);
        }
        bf16x8 ba = *reinterpret_cast<const bf16x8*>(&Bsa[lrow * 40 + lk]);
        acca = __builtin_amdgcn_mfma_f32_16x16x32_bf16(a, ba, acca, 0, 0, 0);
        __syncthreads();
    }
    int r0 = (lane >> 4) * 4;
    {
        int c = lrow, hd = c >> 1;
        float* dsts = (c & 1) ? ad_o : as_o;
#pragma unroll
        for (int r = 0; r < 4; r++) {
            int row = rowBase + wave * 16 + r0 + r;
            if (row < M) dsts[row * HEADS + hd] = acca[r];
        }
    }
    __syncthreads();
    unsigned short* Co = smem;  // [64][264]
#pragma unroll
    for (int j = 0; j < 16; j++)
#pragma unroll
        for (int r = 0; r < 4; r++)
            Co[(wave * 16 + r0 + r) * 264 + j * 16 + lrow] = f2bf(acc[j][r]);
    __syncthreads();
    int wrow = t >> 2, wchunk = (t & 3) * 64;
    int growW = rowBase + wrow;
    if (growW < M) {
#pragma unroll
        for (int q = 0; q < 8; q++) {
            uint4 v = *reinterpret_cast<const uint4*>(&Co[wrow * 264 + wchunk + q * 8]);
            *reinterpret_cast<uint4*>(&Cb[(size_t)growW * 256 + wchunk + q * 8]) = v;
        }
    }
}

// ---------------- GEMM2 MFMA + fused alpha2: out1b [M,256] x W2tb[64,256] -> h2b [M,48], as2/ad2 ----------------
__global__ __launch_bounds__(256) void gemm2_mfma(const unsigned short* __restrict__ Ab,
                                                  const unsigned short* __restrict__ Btb,
                                                  unsigned short* __restrict__ Cb,
                                                  float* __restrict__ as_o,
                                                  float* __restrict__ ad_o, int M) {
    __shared__ unsigned short As[64 * 40];
    __shared__ unsigned short Bs[64 * 40];
    int t = threadIdx.x;
    int wave = t >> 6, lane = t & 63;
    int rowBase = blockIdx.x * 64;
    int lrow = lane & 15, lk = (lane >> 4) * 8;
    f32x4 acc[4] = {};
    int srow = t >> 2, skq = (t & 3) * 8;
    for (int k0 = 0; k0 < 256; k0 += 32) {
        uint4 av = {0, 0, 0, 0};
        int grow = rowBase + srow;
        if (grow < M) av = *reinterpret_cast<const uint4*>(&Ab[(size_t)grow * 256 + k0 + skq]);
        *reinterpret_cast<uint4*>(&As[srow * 40 + skq]) = av;
        uint4 bv = *reinterpret_cast<const uint4*>(&Btb[(size_t)srow * 256 + k0 + skq]);
        *reinterpret_cast<uint4*>(&Bs[srow * 40 + skq]) = bv;
        __syncthreads();
        bf16x8 a = *reinterpret_cast<const bf16x8*>(&As[(wave * 16 + lrow) * 40 + lk]);
#pragma unroll
        for (int j = 0; j < 4; j++) {
            bf16x8 b = *reinterpret_cast<const bf16x8*>(&Bs[(j * 16 + lrow) * 40 + lk]);
            acc[j] = __builtin_amdgcn_mfma_f32_16x16x32_bf16(a, b, acc[j], 0, 0, 0);
        }
        __syncthreads();
    }
    int crow0 = rowBase + wave * 16 + (lane >> 4) * 4;
    int ccol = lane & 15;
#pragma unroll
    for (int j = 0; j < 3; j++)
#pragma unroll
        for (int r = 0; r < 4; r++) {
            int row = crow0 + r;
            if (row < M) Cb[(size_t)row * 48 + j * 16 + ccol] = f2bf(acc[j][r]);
        }
    if (ccol < 2) {
        float* dsts = ccol ? ad_o : as_o;
#pragma unroll
        for (int r = 0; r < 4; r++) {
            int row = crow0 + r;
            if (row < M) dsts[row] = acc[3][r];
        }
    }
}

// ---------------- aggregation layer 1: one wave per node, 8-deep pipelined gather ----------------
__global__ __launch_bounds__(256) void agg1_kernel(const unsigned short* __restrict__ h1b,
                                                   const float* __restrict__ as,
                                                   const float* __restrict__ ad,
                                                   const int* __restrict__ offs,
                                                   const int* __restrict__ adjsrc,
                                                   const float* __restrict__ b,
                                                   unsigned short* __restrict__ outb, int N) {
    int wid = (blockIdx.x * blockDim.x + threadIdx.x) >> 6;
    int lane = threadIdx.x & 63;
    if (wid >= N) return;
    int n = wid;
    int hd = lane >> 3;
    int beg = offs[n], end = offs[n + 1];
    float adh = ad[n * HEADS + hd];
    float ssum = 0.f;
    float4 acc = {0.f, 0.f, 0.f, 0.f};
    int i = beg;
    for (; i + 8 <= end; i += 8) {
        int sidx[8];
        float av[8];
        ushort4 hv[8];
#pragma unroll
        for (int u = 0; u < 8; u++) sidx[u] = adjsrc[i + u];
#pragma unroll
        for (int u = 0; u < 8; u++) av[u] = as[sidx[u] * HEADS + hd];
#pragma unroll
        for (int u = 0; u < 8; u++)
            hv[u] = *reinterpret_cast<const ushort4*>(&h1b[(size_t)sidx[u] * HIDDEN + lane * 4]);
#pragma unroll
        for (int u = 0; u < 8; u++) {
            float e = av[u] + adh;
            e = e > 0.f ? e : 0.2f * e;
            float ex = __expf(e);
            ssum += ex;
            acc.x += ex * bf2f(hv[u].x);
            acc.y += ex * bf2f(hv[u].y);
            acc.z += ex * bf2f(hv[u].z);
            acc.w += ex * bf2f(hv[u].w);
        }
    }
    for (; i + 4 <= end; i += 4) {
        int sidx[4];
        float av[4];
        ushort4 hv[4];
#pragma unroll
        for (int u = 0; u < 4; u++) sidx[u] = adjsrc[i + u];
#pragma unroll
        for (int u = 0; u < 4; u++) av[u] = as[sidx[u] * HEADS + hd];
#pragma unroll
        for (int u = 0; u < 4; u++)
            hv[u] = *reinterpret_cast<const ushort4*>(&h1b[(size_t)sidx[u] * HIDDEN + lane * 4]);
#pragma unroll
        for (int u = 0; u < 4; u++) {
            float e = av[u] + adh;
            e = e > 0.f ? e : 0.2f * e;
            float ex = __expf(e);
            ssum += ex;
            acc.x += ex * bf2f(hv[u].x);
            acc.y += ex * bf2f(hv[u].y);
            acc.z += ex * bf2f(hv[u].z);
            acc.w += ex * bf2f(hv[u].w);
        }
    }
    for (; i < end; i++) {
        int s = adjsrc[i];
        float e = as[s * HEADS + hd] + adh;
        e = e > 0.f ? e : 0.2f * e;
        float ex = __expf(e);
        ssum += ex;
        ushort4 hv = *reinterpret_cast<const ushort4*>(&h1b[(size_t)s * HIDDEN + lane * 4]);
        acc.x += ex * bf2f(hv.x);
        acc.y += ex * bf2f(hv.y);
        acc.z += ex * bf2f(hv.z);
        acc.w += ex * bf2f(hv.w);
    }
    float inv = 1.f / (ssum + 1e-16f);
    int col = lane * 4;
    float4 o;
    o.x = acc.x * inv + b[col + 0];
    o.y = acc.y * inv + b[col + 1];
    o.z = acc.z * inv + b[col + 2];
    o.w = acc.w * inv + b[col + 3];
    o.x = o.x > 0.f ? o.x : expm1f(o.x);
    o.y = o.y > 0.f ? o.y : expm1f(o.y);
    o.z = o.z > 0.f ? o.z : expm1f(o.z);
    o.w = o.w > 0.f ? o.w : expm1f(o.w);
    ushort4 ob;
    ob.x = f2bf(o.x); ob.y = f2bf(o.y); ob.z = f2bf(o.z); ob.w = f2bf(o.w);
    *reinterpret_cast<ushort4*>(&outb[(size_t)n * HIDDEN + col]) = ob;
}

// ---------------- aggregation layer 2: 4-deep pipelined ----------------
__global__ __launch_bounds__(256) void agg2_kernel(const unsigned short* __restrict__ h2b,
                                                   const float* __restrict__ as,
                                                   const float* __restrict__ ad,
                                                   const int* __restrict__ offs,
                                                   const int* __restrict__ adjsrc,
                                                   const float* __restrict__ b,
                                                   float* __restrict__ out, int N) {
    int wid = (blockIdx.x * blockDim.x + threadIdx.x) >> 6;
    int lane = threadIdx.x & 63;
    if (wid >= N) return;
    int n = wid;
    int beg = offs[n], end = offs[n + 1];
    float adh = ad[n];
    float ssum = 0.f;
    float acc = 0.f;
    bool act = lane < NCLS;
    int i = beg;
    for (; i + 4 <= end; i += 4) {
        int s0 = adjsrc[i + 0];
        int s1 = adjsrc[i + 1];
        int s2 = adjsrc[i + 2];
        int s3 = adjsrc[i + 3];
        float a0 = as[s0];
        float a1 = as[s1];
        float a2 = as[s2];
        float a3 = as[s3];
        float h0 = 0.f, h1 = 0.f, h2 = 0.f, h3 = 0.f;
        if (act) {
            h0 = bf2f(h2b[(size_t)s0 * 48 + lane]);
            h1 = bf2f(h2b[(size_t)s1 * 48 + lane]);
            h2 = bf2f(h2b[(size_t)s2 * 48 + lane]);
            h3 = bf2f(h2b[(size_t)s3 * 48 + lane]);
        }
        float e0 = a0 + adh; e0 = e0 > 0.f ? e0 : 0.2f * e0; float x0 = __expf(e0);
        float e1 = a1 + adh; e1 = e1 > 0.f ? e1 : 0.2f * e1; float x1 = __expf(e1);
        float e2 = a2 + adh; e2 = e2 > 0.f ? e2 : 0.2f * e2; float x2 = __expf(e2);
        float e3 = a3 + adh; e3 = e3 > 0.f ? e3 : 0.2f * e3; float x3 = __expf(e3);
        ssum += (x0 + x1) + (x2 + x3);
        acc += x0 * h0 + x1 * h1 + x2 * h2 + x3 * h3;
    }
    for (; i < end; i++) {
        int s = adjsrc[i];
        float e = as[s] + adh;
        e = e > 0.f ? e : 0.2f * e;
        float ex = __expf(e);
        ssum += ex;
        if (act) acc += ex * bf2f(h2b[(size_t)s * 48 + lane]);
    }
    if (act) {
        float inv = 1.f / (ssum + 1e-16f);
        out[(size_t)n * NCLS + lane] = acc * inv + b[lane];
    }
}

extern "C" void kernel_launch(void* const* d_in, const int* in_sizes, int n_in,
                              void* d_out, int out_size, void* d_ws, size_t ws_size,
                              hipStream_t stream) {
    const float* x      = (const float*)d_in[0];
    const int*   ei     = (const int*)d_in[1];
    const float* W1     = (const float*)d_in[2];
    const float* a_src1 = (const float*)d_in[3];
    const float* a_dst1 = (const float*)d_in[4];
    const float* b1     = (const float*)d_in[5];
    const float* W2     = (const float*)d_in[6];
    const float* a_src2 = (const float*)d_in[7];
    const float* a_dst2 = (const float*)d_in[8];
    const float* b2     = (const float*)d_in[9];
    float* out = (float*)d_out;

    const int N = in_sizes[0] / IN_DIM;
    const int E = in_sizes[1] / 2;
    const int* src = ei;
    const int* dst = ei + E;

    char* ws = (char*)d_ws;
    size_t off = 0;
    auto alloc = [&](size_t bytes) {
        void* p = ws + off;
        off = (off + bytes + 255) & ~(size_t)255;
        return p;
    };
    int*   deg    = (int*)alloc((size_t)N * 4);
    int*   excl   = (int*)alloc((size_t)N * 4);
    int*   bsum   = (int*)alloc((size_t)256 * 4);
    int*   cursor = (int*)alloc((size_t)N * 4);
    int*   offs   = (int*)alloc((size_t)(N + 1) * 4);
    int*   adjsrc = (int*)alloc((size_t)E * 4);
    unsigned short* W1tb  = (unsigned short*)alloc((size_t)256 * 256 * 2);
    unsigned short* W2tb  = (unsigned short*)alloc((size_t)64 * 256 * 2);
    unsigned short* Aw    = (unsigned short*)alloc((size_t)16 * 256 * 2);
    unsigned short* h1b   = (unsigned short*)alloc((size_t)N * HIDDEN * 2);
    unsigned short* out1b = (unsigned short*)alloc((size_t)N * HIDDEN * 2);
    unsigned short* h2b   = (unsigned short*)alloc((size_t)N * 48 * 2);
    float* as1    = (float*)alloc((size_t)N * HEADS * 4);
    float* ad1    = (float*)alloc((size_t)N * HEADS * 4);
    float* as2    = (float*)alloc((size_t)N * 4);
    float* ad2    = (float*)alloc((size_t)N * 4);

    const int nb = (N + 1023) / 1024;
    const int ng1 = (N + 63) / 64;

    hipMemsetAsync(deg, 0, (size_t)N * 4, stream);
    hist_kernel<<<dim3((E + 255) / 256), dim3(256), 0, stream>>>(dst, deg, E);
    scan_blocks_kernel<<<dim3(nb), dim3(1024), 0, stream>>>(deg, excl, bsum, N);
    add_base_kernel<<<dim3((N + 256) / 256), dim3(256), 0, stream>>>(excl, bsum, offs, cursor, N, nb);
    fill_kernel<<<dim3((E + 255) / 256), dim3(256), 0, stream>>>(src, dst, cursor, adjsrc, E);

    prep_kernel<<<dim3(320), dim3(256), 0, stream>>>(W1, W2, a_src1, a_dst1, a_src2, a_dst2,
                                                     W1tb, W2tb, Aw);

    gemm1_mfma<<<dim3(ng1), dim3(256), 0, stream>>>(x, W1tb, Aw, h1b, as1, ad1, N);
    agg1_kernel<<<dim3((N + 3) / 4), dim3(256), 0, stream>>>(h1b, as1, ad1, offs, adjsrc, b1, out1b, N);

    gemm2_mfma<<<dim3(ng1), dim3(256), 0, stream>>>(out1b, W2tb, h2b, as2, ad2, N);
    agg2_kernel<<<dim3((N + 3) / 4), dim3(256), 0, stream>>>(h2b, as2, ad2, offs, adjsrc, b2, out, N);
}

// Round 15
// 209.377 us; speedup vs baseline: 1.3040x; 1.2035x over previous
//
#include <hip/hip_runtime.h>
#include <hip/hip_bf16.h>
#include <math.h>

#define IN_DIM 256
#define HIDDEN 256
#define HEADS 8
#define FPH 32
#define NCLS 40

typedef __attribute__((ext_vector_type(8))) short bf16x8;
typedef __attribute__((ext_vector_type(4))) float f32x4;

__device__ inline unsigned short f2bf(float f) {
    unsigned int u = __float_as_uint(f);
    unsigned int r = (u + 0x7FFF + ((u >> 16) & 1)) >> 16;
    return (unsigned short)r;
}
__device__ inline float bf2f(unsigned short u) {
    return __uint_as_float(((unsigned int)u) << 16);
}

// ---------------- CSR build ----------------
// hist also records each edge's within-node rank -> fill needs no atomics.
__global__ void hist_kernel(const int* __restrict__ dst, int* __restrict__ deg,
                            int* __restrict__ rank, int E) {
    int e = blockIdx.x * blockDim.x + threadIdx.x;
    if (e < E) rank[e] = atomicAdd(&deg[dst[e]], 1);
}

__global__ __launch_bounds__(1024) void scan_blocks_kernel(const int* __restrict__ deg,
                                                           int* __restrict__ excl,
                                                           int* __restrict__ bsum, int N) {
    __shared__ int sm[1024];
    int t = threadIdx.x;
    int g = blockIdx.x * 1024 + t;
    int v = (g < N) ? deg[g] : 0;
    sm[t] = v;
    __syncthreads();
    for (int o = 1; o < 1024; o <<= 1) {
        int add = (t >= o) ? sm[t - o] : 0;
        __syncthreads();
        sm[t] += add;
        __syncthreads();
    }
    if (g < N) excl[g] = sm[t] - v;
    if (t == 1023) bsum[blockIdx.x] = sm[1023];
}

__global__ void add_base_kernel(const int* __restrict__ excl, const int* __restrict__ bsum,
                                int* __restrict__ offs, int N, int nb) {
    int g = blockIdx.x * blockDim.x + threadIdx.x;
    if (g > N) return;
    int nblk = g >> 10;
    int lim = (g == N) ? nb : nblk;
    int base = 0;
    for (int i = 0; i < lim; i++) base += bsum[i];
    if (g < N) {
        offs[g] = excl[g] + base;
    } else {
        offs[N] = base;
    }
}

__global__ void fill_kernel(const int* __restrict__ src, const int* __restrict__ dst,
                            const int* __restrict__ rank, const int* __restrict__ offs,
                            int* __restrict__ adjsrc, int E) {
    int e = blockIdx.x * blockDim.x + threadIdx.x;
    if (e < E) {
        int d = dst[e];
        adjsrc[offs[d] + rank[e]] = src[e];
    }
}

// ---------------- prep: W1^T + Aw1 (coalesced shfl reduce), W2tb[64][256] w/ alpha2 cols ----------------
__global__ void prep_kernel(const float* __restrict__ W1, const float* __restrict__ W2,
                            const float* __restrict__ a_src1, const float* __restrict__ a_dst1,
                            const float* __restrict__ a_src2, const float* __restrict__ a_dst2,
                            unsigned short* __restrict__ W1tb, unsigned short* __restrict__ W2tb,
                            unsigned short* __restrict__ Aw) {
    int bid = blockIdx.x;
    int tid = threadIdx.x;
    if (bid < 256) {
        int k = bid, j = tid;
        float w = W1[(size_t)k * 256 + j];
        W1tb[(size_t)j * 256 + k] = f2bf(w);
        float s = w * a_src1[j];
        float d = w * a_dst1[j];
#pragma unroll
        for (int m = 1; m < 32; m <<= 1) {
            s += __shfl_xor(s, m, 64);
            d += __shfl_xor(d, m, 64);
        }
        if ((j & 31) == 0) {
            int hd = j >> 5;
            Aw[(size_t)(2 * hd) * 256 + k]     = f2bf(s);
            Aw[(size_t)(2 * hd + 1) * 256 + k] = f2bf(d);
        }
    } else {
        int c = bid - 256;  // 0..63
        if (c < NCLS) {
            W2tb[(size_t)c * 256 + tid] = f2bf(W2[(size_t)tid * NCLS + c]);
        } else if (c == 48 || c == 49) {
            const float* aptr = (c == 48) ? a_src2 : a_dst2;
            const float* wr = &W2[(size_t)tid * NCLS];
            float s = 0.f;
#pragma unroll
            for (int f = 0; f < NCLS; f++) s += wr[f] * aptr[f];
            W2tb[(size_t)c * 256 + tid] = f2bf(s);
        } else {
            W2tb[(size_t)c * 256 + tid] = 0;
        }
    }
}

// ---------------- GEMM1 MFMA + fused alpha1 ----------------
__global__ __launch_bounds__(256) void gemm1_mfma(const float* __restrict__ A,
                                                  const unsigned short* __restrict__ Btb,
                                                  const unsigned short* __restrict__ Aw,
                                                  unsigned short* __restrict__ Cb,
                                                  float* __restrict__ as_o,
                                                  float* __restrict__ ad_o, int M) {
    __shared__ unsigned short smem[64 * 264];  // 16896 >= 13440
    unsigned short* As = smem;
    unsigned short* Bs = smem + 64 * 40;
    unsigned short* Bsa = smem + 64 * 40 + 256 * 40;
    int t = threadIdx.x;
    int wave = t >> 6, lane = t & 63;
    int rowBase = blockIdx.x * 64;
    int lrow = lane & 15, lk = (lane >> 4) * 8;
    f32x4 acc[16] = {};
    f32x4 acca = {};
    int arow = t >> 2, akq = (t & 3) * 8;
    for (int k0 = 0; k0 < 256; k0 += 32) {
        int grow = rowBase + arow;
        float4 a0 = {0.f, 0.f, 0.f, 0.f}, a1 = {0.f, 0.f, 0.f, 0.f};
        if (grow < M) {
            a0 = *reinterpret_cast<const float4*>(&A[(size_t)grow * 256 + k0 + akq]);
            a1 = *reinterpret_cast<const float4*>(&A[(size_t)grow * 256 + k0 + akq + 4]);
        }
        ushort4 p0 = {f2bf(a0.x), f2bf(a0.y), f2bf(a0.z), f2bf(a0.w)};
        ushort4 p1 = {f2bf(a1.x), f2bf(a1.y), f2bf(a1.z), f2bf(a1.w)};
        *reinterpret_cast<ushort4*>(&As[arow * 40 + akq]) = p0;
        *reinterpret_cast<ushort4*>(&As[arow * 40 + akq + 4]) = p1;
#pragma unroll
        for (int q = 0; q < 4; q++) {
            uint4 bv = *reinterpret_cast<const uint4*>(&Btb[(size_t)t * 256 + k0 + q * 8]);
            *reinterpret_cast<uint4*>(&Bs[t * 40 + q * 8]) = bv;
        }
        if (t < 16) {
#pragma unroll
            for (int q = 0; q < 4; q++) {
                uint4 av = *reinterpret_cast<const uint4*>(&Aw[(size_t)t * 256 + k0 + q * 8]);
                *reinterpret_cast<uint4*>(&Bsa[t * 40 + q * 8]) = av;
            }
        }
        __syncthreads();
        bf16x8 a = *reinterpret_cast<const bf16x8*>(&As[(wave * 16 + lrow) * 40 + lk]);
#pragma unroll
        for (int j = 0; j < 16; j++) {
            bf16x8 b = *reinterpret_cast<const bf16x8*>(&Bs[(j * 16 + lrow) * 40 + lk]);
            acc[j] = __builtin_amdgcn_mfma_f32_16x16x32_bf16(a, b, acc[j], 0, 0, 0);
        }
        bf16x8 ba = *reinterpret_cast<const bf16x8*>(&Bsa[lrow * 40 + lk]);
        acca = __builtin_amdgcn_mfma_f32_16x16x32_bf16(a, ba, acca, 0, 0, 0);
        __syncthreads();
    }
    int r0 = (lane >> 4) * 4;
    {
        int c = lrow, hd = c >> 1;
        float* dsts = (c & 1) ? ad_o : as_o;
#pragma unroll
        for (int r = 0; r < 4; r++) {
            int row = rowBase + wave * 16 + r0 + r;
            if (row < M) dsts[row * HEADS + hd] = acca[r];
        }
    }
    __syncthreads();
    unsigned short* Co = smem;  // [64][264]
#pragma unroll
    for (int j = 0; j < 16; j++)
#pragma unroll
        for (int r = 0; r < 4; r++)
            Co[(wave * 16 + r0 + r) * 264 + j * 16 + lrow] = f2bf(acc[j][r]);
    __syncthreads();
    int wrow = t >> 2, wchunk = (t & 3) * 64;
    int growW = rowBase + wrow;
    if (growW < M) {
#pragma unroll
        for (int q = 0; q < 8; q++) {
            uint4 v = *reinterpret_cast<const uint4*>(&Co[wrow * 264 + wchunk + q * 8]);
            *reinterpret_cast<uint4*>(&Cb[(size_t)growW * 256 + wchunk + q * 8]) = v;
        }
    }
}

// ---------------- GEMM2 MFMA + fused alpha2 ----------------
__global__ __launch_bounds__(256) void gemm2_mfma(const unsigned short* __restrict__ Ab,
                                                  const unsigned short* __restrict__ Btb,
                                                  unsigned short* __restrict__ Cb,
                                                  float* __restrict__ as_o,
                                                  float* __restrict__ ad_o, int M) {
    __shared__ unsigned short As[64 * 40];
    __shared__ unsigned short Bs[64 * 40];
    int t = threadIdx.x;
    int wave = t >> 6, lane = t & 63;
    int rowBase = blockIdx.x * 64;
    int lrow = lane & 15, lk = (lane >> 4) * 8;
    f32x4 acc[4] = {};
    int srow = t >> 2, skq = (t & 3) * 8;
    for (int k0 = 0; k0 < 256; k0 += 32) {
        uint4 av = {0, 0, 0, 0};
        int grow = rowBase + srow;
        if (grow < M) av = *reinterpret_cast<const uint4*>(&Ab[(size_t)grow * 256 + k0 + skq]);
        *reinterpret_cast<uint4*>(&As[srow * 40 + skq]) = av;
        uint4 bv = *reinterpret_cast<const uint4*>(&Btb[(size_t)srow * 256 + k0 + skq]);
        *reinterpret_cast<uint4*>(&Bs[srow * 40 + skq]) = bv;
        __syncthreads();
        bf16x8 a = *reinterpret_cast<const bf16x8*>(&As[(wave * 16 + lrow) * 40 + lk]);
#pragma unroll
        for (int j = 0; j < 4; j++) {
            bf16x8 b = *reinterpret_cast<const bf16x8*>(&Bs[(j * 16 + lrow) * 40 + lk]);
            acc[j] = __builtin_amdgcn_mfma_f32_16x16x32_bf16(a, b, acc[j], 0, 0, 0);
        }
        __syncthreads();
    }
    int crow0 = rowBase + wave * 16 + (lane >> 4) * 4;
    int ccol = lane & 15;
#pragma unroll
    for (int j = 0; j < 3; j++)
#pragma unroll
        for (int r = 0; r < 4; r++) {
            int row = crow0 + r;
            if (row < M) Cb[(size_t)row * 48 + j * 16 + ccol] = f2bf(acc[j][r]);
        }
    if (ccol < 2) {
        float* dsts = ccol ? ad_o : as_o;
#pragma unroll
        for (int r = 0; r < 4; r++) {
            int row = crow0 + r;
            if (row < M) dsts[row] = acc[3][r];
        }
    }
}

// ---------------- aggregation layer 1: one wave per node, 8-deep pipelined gather ----------------
__global__ __launch_bounds__(256) void agg1_kernel(const unsigned short* __restrict__ h1b,
                                                   const float* __restrict__ as,
                                                   const float* __restrict__ ad,
                                                   const int* __restrict__ offs,
                                                   const int* __restrict__ adjsrc,
                                                   const float* __restrict__ b,
                                                   unsigned short* __restrict__ outb, int N) {
    int wid = (blockIdx.x * blockDim.x + threadIdx.x) >> 6;
    int lane = threadIdx.x & 63;
    if (wid >= N) return;
    int n = wid;
    int hd = lane >> 3;
    int beg = offs[n], end = offs[n + 1];
    float adh = ad[n * HEADS + hd];
    float ssum = 0.f;
    float4 acc = {0.f, 0.f, 0.f, 0.f};
    int i = beg;
    for (; i + 8 <= end; i += 8) {
        int sidx[8];
        float av[8];
        ushort4 hv[8];
#pragma unroll
        for (int u = 0; u < 8; u++) sidx[u] = adjsrc[i + u];
#pragma unroll
        for (int u = 0; u < 8; u++) av[u] = as[sidx[u] * HEADS + hd];
#pragma unroll
        for (int u = 0; u < 8; u++)
            hv[u] = *reinterpret_cast<const ushort4*>(&h1b[(size_t)sidx[u] * HIDDEN + lane * 4]);
#pragma unroll
        for (int u = 0; u < 8; u++) {
            float e = av[u] + adh;
            e = e > 0.f ? e : 0.2f * e;
            float ex = __expf(e);
            ssum += ex;
            acc.x += ex * bf2f(hv[u].x);
            acc.y += ex * bf2f(hv[u].y);
            acc.z += ex * bf2f(hv[u].z);
            acc.w += ex * bf2f(hv[u].w);
        }
    }
    for (; i + 4 <= end; i += 4) {
        int sidx[4];
        float av[4];
        ushort4 hv[4];
#pragma unroll
        for (int u = 0; u < 4; u++) sidx[u] = adjsrc[i + u];
#pragma unroll
        for (int u = 0; u < 4; u++) av[u] = as[sidx[u] * HEADS + hd];
#pragma unroll
        for (int u = 0; u < 4; u++)
            hv[u] = *reinterpret_cast<const ushort4*>(&h1b[(size_t)sidx[u] * HIDDEN + lane * 4]);
#pragma unroll
        for (int u = 0; u < 4; u++) {
            float e = av[u] + adh;
            e = e > 0.f ? e : 0.2f * e;
            float ex = __expf(e);
            ssum += ex;
            acc.x += ex * bf2f(hv[u].x);
            acc.y += ex * bf2f(hv[u].y);
            acc.z += ex * bf2f(hv[u].z);
            acc.w += ex * bf2f(hv[u].w);
        }
    }
    for (; i < end; i++) {
        int s = adjsrc[i];
        float e = as[s * HEADS + hd] + adh;
        e = e > 0.f ? e : 0.2f * e;
        float ex = __expf(e);
        ssum += ex;
        ushort4 hv = *reinterpret_cast<const ushort4*>(&h1b[(size_t)s * HIDDEN + lane * 4]);
        acc.x += ex * bf2f(hv.x);
        acc.y += ex * bf2f(hv.y);
        acc.z += ex * bf2f(hv.z);
        acc.w += ex * bf2f(hv.w);
    }
    float inv = 1.f / (ssum + 1e-16f);
    int col = lane * 4;
    float4 o;
    o.x = acc.x * inv + b[col + 0];
    o.y = acc.y * inv + b[col + 1];
    o.z = acc.z * inv + b[col + 2];
    o.w = acc.w * inv + b[col + 3];
    o.x = o.x > 0.f ? o.x : expm1f(o.x);
    o.y = o.y > 0.f ? o.y : expm1f(o.y);
    o.z = o.z > 0.f ? o.z : expm1f(o.z);
    o.w = o.w > 0.f ? o.w : expm1f(o.w);
    ushort4 ob;
    ob.x = f2bf(o.x); ob.y = f2bf(o.y); ob.z = f2bf(o.z); ob.w = f2bf(o.w);
    *reinterpret_cast<ushort4*>(&outb[(size_t)n * HIDDEN + col]) = ob;
}

// ---------------- aggregation layer 2: half-wave (2 edges/iter), packed-uint loads ----------------
// h2b is L2-resident (4.8 MB) -> instruction-bound, not traffic-bound: thinner per-edge work pays.
__global__ __launch_bounds__(256) void agg2_kernel(const unsigned short* __restrict__ h2b,
                                                   const float* __restrict__ as,
                                                   const float* __restrict__ ad,
                                                   const int* __restrict__ offs,
                                                   const int* __restrict__ adjsrc,
                                                   const float* __restrict__ b,
                                                   float* __restrict__ out, int N) {
    int wid = (blockIdx.x * blockDim.x + threadIdx.x) >> 6;
    int lane = threadIdx.x & 63;
    if (wid >= N) return;
    int n = wid;
    int half = lane >> 5;
    int l = lane & 31;          // class pair index: classes 2l, 2l+1 (active l<20)
    bool act = l < 20;
    int beg = offs[n], end = offs[n + 1];
    float adh = ad[n];
    float ssum = 0.f;
    float acc0 = 0.f, acc1 = 0.f;
    int i = beg;
    for (; i + 8 <= end; i += 8) {
        int sidx[4];
        float av[4];
        unsigned int hv[4];
#pragma unroll
        for (int u = 0; u < 4; u++) sidx[u] = adjsrc[i + 2 * u + half];
#pragma unroll
        for (int u = 0; u < 4; u++) av[u] = as[sidx[u]];
#pragma unroll
        for (int u = 0; u < 4; u++)
            hv[u] = act ? *reinterpret_cast<const unsigned int*>(&h2b[(size_t)sidx[u] * 48 + l * 2]) : 0u;
#pragma unroll
        for (int u = 0; u < 4; u++) {
            float e = av[u] + adh;
            e = e > 0.f ? e : 0.2f * e;
            float ex = __expf(e);
            ssum += ex;
            acc0 += ex * __uint_as_float(hv[u] << 16);
            acc1 += ex * __uint_as_float(hv[u] & 0xffff0000u);
        }
    }
    for (; i < end; i += 2) {
        int idx = i + half;
        if (idx < end) {
            int s = adjsrc[idx];
            float e = as[s] + adh;
            e = e > 0.f ? e : 0.2f * e;
            float ex = __expf(e);
            ssum += ex;
            unsigned int hv = act ? *reinterpret_cast<const unsigned int*>(&h2b[(size_t)s * 48 + l * 2]) : 0u;
            acc0 += ex * __uint_as_float(hv << 16);
            acc1 += ex * __uint_as_float(hv & 0xffff0000u);
        }
    }
    acc0 += __shfl_xor(acc0, 32, 64);
    acc1 += __shfl_xor(acc1, 32, 64);
    ssum += __shfl_xor(ssum, 32, 64);
    if (half == 0 && act) {
        float inv = 1.f / (ssum + 1e-16f);
        float2 o;
        o.x = acc0 * inv + b[2 * l];
        o.y = acc1 * inv + b[2 * l + 1];
        *reinterpret_cast<float2*>(&out[(size_t)n * NCLS + 2 * l]) = o;
    }
}

extern "C" void kernel_launch(void* const* d_in, const int* in_sizes, int n_in,
                              void* d_out, int out_size, void* d_ws, size_t ws_size,
                              hipStream_t stream) {
    const float* x      = (const float*)d_in[0];
    const int*   ei     = (const int*)d_in[1];
    const float* W1     = (const float*)d_in[2];
    const float* a_src1 = (const float*)d_in[3];
    const float* a_dst1 = (const float*)d_in[4];
    const float* b1     = (const float*)d_in[5];
    const float* W2     = (const float*)d_in[6];
    const float* a_src2 = (const float*)d_in[7];
    const float* a_dst2 = (const float*)d_in[8];
    const float* b2     = (const float*)d_in[9];
    float* out = (float*)d_out;

    const int N = in_sizes[0] / IN_DIM;
    const int E = in_sizes[1] / 2;
    const int* src = ei;
    const int* dst = ei + E;

    char* ws = (char*)d_ws;
    size_t off = 0;
    auto alloc = [&](size_t bytes) {
        void* p = ws + off;
        off = (off + bytes + 255) & ~(size_t)255;
        return p;
    };
    int*   deg    = (int*)alloc((size_t)N * 4);
    int*   excl   = (int*)alloc((size_t)N * 4);
    int*   bsum   = (int*)alloc((size_t)256 * 4);
    int*   rank   = (int*)alloc((size_t)E * 4);
    int*   offs   = (int*)alloc((size_t)(N + 1) * 4);
    int*   adjsrc = (int*)alloc((size_t)E * 4);
    unsigned short* W1tb  = (unsigned short*)alloc((size_t)256 * 256 * 2);
    unsigned short* W2tb  = (unsigned short*)alloc((size_t)64 * 256 * 2);
    unsigned short* Aw    = (unsigned short*)alloc((size_t)16 * 256 * 2);
    unsigned short* h1b   = (unsigned short*)alloc((size_t)N * HIDDEN * 2);
    unsigned short* out1b = (unsigned short*)alloc((size_t)N * HIDDEN * 2);
    unsigned short* h2b   = (unsigned short*)alloc((size_t)N * 48 * 2);
    float* as1    = (float*)alloc((size_t)N * HEADS * 4);
    float* ad1    = (float*)alloc((size_t)N * HEADS * 4);
    float* as2    = (float*)alloc((size_t)N * 4);
    float* ad2    = (float*)alloc((size_t)N * 4);

    const int nb = (N + 1023) / 1024;
    const int ng1 = (N + 63) / 64;

    hipMemsetAsync(deg, 0, (size_t)N * 4, stream);
    hist_kernel<<<dim3((E + 255) / 256), dim3(256), 0, stream>>>(dst, deg, rank, E);
    scan_blocks_kernel<<<dim3(nb), dim3(1024), 0, stream>>>(deg, excl, bsum, N);
    add_base_kernel<<<dim3((N + 256) / 256), dim3(256), 0, stream>>>(excl, bsum, offs, N, nb);
    fill_kernel<<<dim3((E + 255) / 256), dim3(256), 0, stream>>>(src, dst, rank, offs, adjsrc, E);

    prep_kernel<<<dim3(320), dim3(256), 0, stream>>>(W1, W2, a_src1, a_dst1, a_src2, a_dst2,
                                                     W1tb, W2tb, Aw);

    gemm1_mfma<<<dim3(ng1), dim3(256), 0, stream>>>(x, W1tb, Aw, h1b, as1, ad1, N);
    agg1_kernel<<<dim3((N + 3) / 4), dim3(256), 0, stream>>>(h1b, as1, ad1, offs, adjsrc, b1, out1b, N);

    gemm2_mfma<<<dim3(ng1), dim3(256), 0, stream>>>(out1b, W2tb, h2b, as2, ad2, N);
    agg2_kernel<<<dim3((N + 3) / 4), dim3(256), 0, stream>>>(h2b, as2, ad2, offs, adjsrc, b2, out, N);
}

// Round 16
// 203.854 us; speedup vs baseline: 1.3393x; 1.0271x over previous
//
#include <hip/hip_runtime.h>
#include <hip/hip_bf16.h>
#include <math.h>

#define IN_DIM 256
#define HIDDEN 256
#define HEADS 8
#define FPH 32
#define NCLS 40

typedef __attribute__((ext_vector_type(8))) short bf16x8;
typedef __attribute__((ext_vector_type(4))) float f32x4;

__device__ inline unsigned short f2bf(float f) {
    unsigned int u = __float_as_uint(f);
    unsigned int r = (u + 0x7FFF + ((u >> 16) & 1)) >> 16;
    return (unsigned short)r;
}
__device__ inline float bf2f(unsigned short u) {
    return __uint_as_float(((unsigned int)u) << 16);
}

// ---------------- histprep: hist (blocks < nhist) || prep (LDS-free union; R13's failure
// mechanism was stage2's 33KB LDS throttling fill occupancy — absent here) ----------------
__global__ void histprep_kernel(const int* __restrict__ dst, int* __restrict__ deg,
                                int* __restrict__ rank, int E,
                                const float* __restrict__ W1, const float* __restrict__ W2,
                                const float* __restrict__ a_src1, const float* __restrict__ a_dst1,
                                const float* __restrict__ a_src2, const float* __restrict__ a_dst2,
                                unsigned short* __restrict__ W1tb, unsigned short* __restrict__ W2tb,
                                unsigned short* __restrict__ Aw, int nhist) {
    int bid = blockIdx.x;
    int tid = threadIdx.x;
    if (bid < nhist) {
        int e = bid * 256 + tid;
        if (e < E) rank[e] = atomicAdd(&deg[dst[e]], 1);
        return;
    }
    int pbid = bid - nhist;
    if (pbid < 256) {
        int k = pbid, j = tid;
        float w = W1[(size_t)k * 256 + j];
        W1tb[(size_t)j * 256 + k] = f2bf(w);
        float s = w * a_src1[j];
        float d = w * a_dst1[j];
#pragma unroll
        for (int m = 1; m < 32; m <<= 1) {
            s += __shfl_xor(s, m, 64);
            d += __shfl_xor(d, m, 64);
        }
        if ((j & 31) == 0) {
            int hd = j >> 5;
            Aw[(size_t)(2 * hd) * 256 + k]     = f2bf(s);
            Aw[(size_t)(2 * hd + 1) * 256 + k] = f2bf(d);
        }
    } else {
        int c = pbid - 256;  // 0..63
        if (c < NCLS) {
            W2tb[(size_t)c * 256 + tid] = f2bf(W2[(size_t)tid * NCLS + c]);
        } else if (c == 48 || c == 49) {
            const float* aptr = (c == 48) ? a_src2 : a_dst2;
            const float* wr = &W2[(size_t)tid * NCLS];
            float s = 0.f;
#pragma unroll
            for (int f = 0; f < NCLS; f++) s += wr[f] * aptr[f];
            W2tb[(size_t)c * 256 + tid] = f2bf(s);
        } else {
            W2tb[(size_t)c * 256 + tid] = 0;
        }
    }
}

__global__ __launch_bounds__(1024) void scan_blocks_kernel(const int* __restrict__ deg,
                                                           int* __restrict__ excl,
                                                           int* __restrict__ bsum, int N) {
    __shared__ int sm[1024];
    int t = threadIdx.x;
    int g = blockIdx.x * 1024 + t;
    int v = (g < N) ? deg[g] : 0;
    sm[t] = v;
    __syncthreads();
    for (int o = 1; o < 1024; o <<= 1) {
        int add = (t >= o) ? sm[t - o] : 0;
        __syncthreads();
        sm[t] += add;
        __syncthreads();
    }
    if (g < N) excl[g] = sm[t] - v;
    if (t == 1023) bsum[blockIdx.x] = sm[1023];
}

__global__ void add_base_kernel(const int* __restrict__ excl, const int* __restrict__ bsum,
                                int* __restrict__ offs, int N, int nb) {
    int g = blockIdx.x * blockDim.x + threadIdx.x;
    if (g > N) return;
    int nblk = g >> 10;
    int lim = (g == N) ? nb : nblk;
    int base = 0;
    for (int i = 0; i < lim; i++) base += bsum[i];
    if (g < N) {
        offs[g] = excl[g] + base;
    } else {
        offs[N] = base;
    }
}

__global__ void fill_kernel(const int* __restrict__ src, const int* __restrict__ dst,
                            const int* __restrict__ rank, const int* __restrict__ offs,
                            int* __restrict__ adjsrc, int E) {
    int e = blockIdx.x * blockDim.x + threadIdx.x;
    if (e < E) {
        int d = dst[e];
        adjsrc[offs[d] + rank[e]] = src[e];
    }
}

// ---------------- GEMM1 MFMA + fused alpha1: 128 rows/block, 512 threads (8 waves) ----------------
// Halves per-row B-restage vs 64-row blocks. LDS 33KB -> 4 blocks/CU at 512 thr.
__global__ __launch_bounds__(512) void gemm1_mfma(const float* __restrict__ A,
                                                  const unsigned short* __restrict__ Btb,
                                                  const unsigned short* __restrict__ Aw,
                                                  unsigned short* __restrict__ Cb,
                                                  float* __restrict__ as_o,
                                                  float* __restrict__ ad_o, int M) {
    __shared__ unsigned short smem[16896];  // K-loop: As 5120 + Bs 10240 + Bsa 640 = 16000; epi: Co 64*264=16896
    unsigned short* As = smem;               // [128][40]
    unsigned short* Bs = smem + 128 * 40;    // [256][40]
    unsigned short* Bsa = smem + 128 * 40 + 256 * 40;  // [16][40]
    int t = threadIdx.x;
    int wave = t >> 6, lane = t & 63;
    int rowBase = blockIdx.x * 128;
    int lrow = lane & 15, lk = (lane >> 4) * 8;
    f32x4 acc[16] = {};
    f32x4 acca = {};
    int arow = t >> 2, akq = (t & 3) * 8;      // 512 thr -> 128 rows x 4 k-chunks
    int bcol = t >> 1, bh = (t & 1) * 16;      // 512 thr -> 256 cols x 2 halves
    for (int k0 = 0; k0 < 256; k0 += 32) {
        int grow = rowBase + arow;
        float4 a0 = {0.f, 0.f, 0.f, 0.f}, a1 = {0.f, 0.f, 0.f, 0.f};
        if (grow < M) {
            a0 = *reinterpret_cast<const float4*>(&A[(size_t)grow * 256 + k0 + akq]);
            a1 = *reinterpret_cast<const float4*>(&A[(size_t)grow * 256 + k0 + akq + 4]);
        }
        ushort4 p0 = {f2bf(a0.x), f2bf(a0.y), f2bf(a0.z), f2bf(a0.w)};
        ushort4 p1 = {f2bf(a1.x), f2bf(a1.y), f2bf(a1.z), f2bf(a1.w)};
        *reinterpret_cast<ushort4*>(&As[arow * 40 + akq]) = p0;
        *reinterpret_cast<ushort4*>(&As[arow * 40 + akq + 4]) = p1;
        {
            uint4 bv0 = *reinterpret_cast<const uint4*>(&Btb[(size_t)bcol * 256 + k0 + bh]);
            uint4 bv1 = *reinterpret_cast<const uint4*>(&Btb[(size_t)bcol * 256 + k0 + bh + 8]);
            *reinterpret_cast<uint4*>(&Bs[bcol * 40 + bh]) = bv0;
            *reinterpret_cast<uint4*>(&Bs[bcol * 40 + bh + 8]) = bv1;
        }
        if (t < 16) {
#pragma unroll
            for (int q = 0; q < 4; q++) {
                uint4 av = *reinterpret_cast<const uint4*>(&Aw[(size_t)t * 256 + k0 + q * 8]);
                *reinterpret_cast<uint4*>(&Bsa[t * 40 + q * 8]) = av;
            }
        }
        __syncthreads();
        bf16x8 a = *reinterpret_cast<const bf16x8*>(&As[(wave * 16 + lrow) * 40 + lk]);
#pragma unroll
        for (int j = 0; j < 16; j++) {
            bf16x8 b = *reinterpret_cast<const bf16x8*>(&Bs[(j * 16 + lrow) * 40 + lk]);
            acc[j] = __builtin_amdgcn_mfma_f32_16x16x32_bf16(a, b, acc[j], 0, 0, 0);
        }
        bf16x8 ba = *reinterpret_cast<const bf16x8*>(&Bsa[lrow * 40 + lk]);
        acca = __builtin_amdgcn_mfma_f32_16x16x32_bf16(a, ba, acca, 0, 0, 0);
        __syncthreads();
    }
    int r0 = (lane >> 4) * 4;
    {
        int c = lrow, hd = c >> 1;
        float* dsts = (c & 1) ? ad_o : as_o;
#pragma unroll
        for (int r = 0; r < 4; r++) {
            int row = rowBase + wave * 16 + r0 + r;
            if (row < M) dsts[row * HEADS + hd] = acca[r];
        }
    }
    // C epilogue in two 64-row halves through Co[64][264]
    unsigned short* Co = smem;
#pragma unroll
    for (int h = 0; h < 2; h++) {
        __syncthreads();
        if ((wave >> 2) == h) {
            int lw = wave & 3;
#pragma unroll
            for (int j = 0; j < 16; j++)
#pragma unroll
                for (int r = 0; r < 4; r++)
                    Co[(lw * 16 + r0 + r) * 264 + j * 16 + lrow] = f2bf(acc[j][r]);
        }
        __syncthreads();
        int wrow = t >> 3, wchunk = (t & 7) * 32;
        int row = rowBase + h * 64 + wrow;
        if (row < M) {
#pragma unroll
            for (int q = 0; q < 4; q++) {
                uint4 v = *reinterpret_cast<const uint4*>(&Co[wrow * 264 + wchunk + q * 8]);
                *reinterpret_cast<uint4*>(&Cb[(size_t)row * 256 + wchunk + q * 8]) = v;
            }
        }
    }
}

// ---------------- GEMM2 MFMA + fused alpha2 ----------------
__global__ __launch_bounds__(256) void gemm2_mfma(const unsigned short* __restrict__ Ab,
                                                  const unsigned short* __restrict__ Btb,
                                                  unsigned short* __restrict__ Cb,
                                                  float* __restrict__ as_o,
                                                  float* __restrict__ ad_o, int M) {
    __shared__ unsigned short As[64 * 40];
    __shared__ unsigned short Bs[64 * 40];
    int t = threadIdx.x;
    int wave = t >> 6, lane = t & 63;
    int rowBase = blockIdx.x * 64;
    int lrow = lane & 15, lk = (lane >> 4) * 8;
    f32x4 acc[4] = {};
    int srow = t >> 2, skq = (t & 3) * 8;
    for (int k0 = 0; k0 < 256; k0 += 32) {
        uint4 av = {0, 0, 0, 0};
        int grow = rowBase + srow;
        if (grow < M) av = *reinterpret_cast<const uint4*>(&Ab[(size_t)grow * 256 + k0 + skq]);
        *reinterpret_cast<uint4*>(&As[srow * 40 + skq]) = av;
        uint4 bv = *reinterpret_cast<const uint4*>(&Btb[(size_t)srow * 256 + k0 + skq]);
        *reinterpret_cast<uint4*>(&Bs[srow * 40 + skq]) = bv;
        __syncthreads();
        bf16x8 a = *reinterpret_cast<const bf16x8*>(&As[(wave * 16 + lrow) * 40 + lk]);
#pragma unroll
        for (int j = 0; j < 4; j++) {
            bf16x8 b = *reinterpret_cast<const bf16x8*>(&Bs[(j * 16 + lrow) * 40 + lk]);
            acc[j] = __builtin_amdgcn_mfma_f32_16x16x32_bf16(a, b, acc[j], 0, 0, 0);
        }
        __syncthreads();
    }
    int crow0 = rowBase + wave * 16 + (lane >> 4) * 4;
    int ccol = lane & 15;
#pragma unroll
    for (int j = 0; j < 3; j++)
#pragma unroll
        for (int r = 0; r < 4; r++) {
            int row = crow0 + r;
            if (row < M) Cb[(size_t)row * 48 + j * 16 + ccol] = f2bf(acc[j][r]);
        }
    if (ccol < 2) {
        float* dsts = ccol ? ad_o : as_o;
#pragma unroll
        for (int r = 0; r < 4; r++) {
            int row = crow0 + r;
            if (row < M) dsts[row] = acc[3][r];
        }
    }
}

// ---------------- aggregation layer 1: one wave per node, 8-deep pipelined gather ----------------
__global__ __launch_bounds__(256) void agg1_kernel(const unsigned short* __restrict__ h1b,
                                                   const float* __restrict__ as,
                                                   const float* __restrict__ ad,
                                                   const int* __restrict__ offs,
                                                   const int* __restrict__ adjsrc,
                                                   const float* __restrict__ b,
                                                   unsigned short* __restrict__ outb, int N) {
    int wid = (blockIdx.x * blockDim.x + threadIdx.x) >> 6;
    int lane = threadIdx.x & 63;
    if (wid >= N) return;
    int n = wid;
    int hd = lane >> 3;
    int beg = offs[n], end = offs[n + 1];
    float adh = ad[n * HEADS + hd];
    float ssum = 0.f;
    float4 acc = {0.f, 0.f, 0.f, 0.f};
    int i = beg;
    for (; i + 8 <= end; i += 8) {
        int sidx[8];
        float av[8];
        ushort4 hv[8];
#pragma unroll
        for (int u = 0; u < 8; u++) sidx[u] = adjsrc[i + u];
#pragma unroll
        for (int u = 0; u < 8; u++) av[u] = as[sidx[u] * HEADS + hd];
#pragma unroll
        for (int u = 0; u < 8; u++)
            hv[u] = *reinterpret_cast<const ushort4*>(&h1b[(size_t)sidx[u] * HIDDEN + lane * 4]);
#pragma unroll
        for (int u = 0; u < 8; u++) {
            float e = av[u] + adh;
            e = e > 0.f ? e : 0.2f * e;
            float ex = __expf(e);
            ssum += ex;
            acc.x += ex * bf2f(hv[u].x);
            acc.y += ex * bf2f(hv[u].y);
            acc.z += ex * bf2f(hv[u].z);
            acc.w += ex * bf2f(hv[u].w);
        }
    }
    for (; i + 4 <= end; i += 4) {
        int sidx[4];
        float av[4];
        ushort4 hv[4];
#pragma unroll
        for (int u = 0; u < 4; u++) sidx[u] = adjsrc[i + u];
#pragma unroll
        for (int u = 0; u < 4; u++) av[u] = as[sidx[u] * HEADS + hd];
#pragma unroll
        for (int u = 0; u < 4; u++)
            hv[u] = *reinterpret_cast<const ushort4*>(&h1b[(size_t)sidx[u] * HIDDEN + lane * 4]);
#pragma unroll
        for (int u = 0; u < 4; u++) {
            float e = av[u] + adh;
            e = e > 0.f ? e : 0.2f * e;
            float ex = __expf(e);
            ssum += ex;
            acc.x += ex * bf2f(hv[u].x);
            acc.y += ex * bf2f(hv[u].y);
            acc.z += ex * bf2f(hv[u].z);
            acc.w += ex * bf2f(hv[u].w);
        }
    }
    for (; i < end; i++) {
        int s = adjsrc[i];
        float e = as[s * HEADS + hd] + adh;
        e = e > 0.f ? e : 0.2f * e;
        float ex = __expf(e);
        ssum += ex;
        ushort4 hv = *reinterpret_cast<const ushort4*>(&h1b[(size_t)s * HIDDEN + lane * 4]);
        acc.x += ex * bf2f(hv.x);
        acc.y += ex * bf2f(hv.y);
        acc.z += ex * bf2f(hv.z);
        acc.w += ex * bf2f(hv.w);
    }
    float inv = 1.f / (ssum + 1e-16f);
    int col = lane * 4;
    float4 o;
    o.x = acc.x * inv + b[col + 0];
    o.y = acc.y * inv + b[col + 1];
    o.z = acc.z * inv + b[col + 2];
    o.w = acc.w * inv + b[col + 3];
    o.x = o.x > 0.f ? o.x : expm1f(o.x);
    o.y = o.y > 0.f ? o.y : expm1f(o.y);
    o.z = o.z > 0.f ? o.z : expm1f(o.z);
    o.w = o.w > 0.f ? o.w : expm1f(o.w);
    ushort4 ob;
    ob.x = f2bf(o.x); ob.y = f2bf(o.y); ob.z = f2bf(o.z); ob.w = f2bf(o.w);
    *reinterpret_cast<ushort4*>(&outb[(size_t)n * HIDDEN + col]) = ob;
}

// ---------------- aggregation layer 2: half-wave (2 edges/iter), packed-uint loads ----------------
__global__ __launch_bounds__(256) void agg2_kernel(const unsigned short* __restrict__ h2b,
                                                   const float* __restrict__ as,
                                                   const float* __restrict__ ad,
                                                   const int* __restrict__ offs,
                                                   const int* __restrict__ adjsrc,
                                                   const float* __restrict__ b,
                                                   float* __restrict__ out, int N) {
    int wid = (blockIdx.x * blockDim.x + threadIdx.x) >> 6;
    int lane = threadIdx.x & 63;
    if (wid >= N) return;
    int n = wid;
    int half = lane >> 5;
    int l = lane & 31;
    bool act = l < 20;
    int beg = offs[n], end = offs[n + 1];
    float adh = ad[n];
    float ssum = 0.f;
    float acc0 = 0.f, acc1 = 0.f;
    int i = beg;
    for (; i + 8 <= end; i += 8) {
        int sidx[4];
        float av[4];
        unsigned int hv[4];
#pragma unroll
        for (int u = 0; u < 4; u++) sidx[u] = adjsrc[i + 2 * u + half];
#pragma unroll
        for (int u = 0; u < 4; u++) av[u] = as[sidx[u]];
#pragma unroll
        for (int u = 0; u < 4; u++)
            hv[u] = act ? *reinterpret_cast<const unsigned int*>(&h2b[(size_t)sidx[u] * 48 + l * 2]) : 0u;
#pragma unroll
        for (int u = 0; u < 4; u++) {
            float e = av[u] + adh;
            e = e > 0.f ? e : 0.2f * e;
            float ex = __expf(e);
            ssum += ex;
            acc0 += ex * __uint_as_float(hv[u] << 16);
            acc1 += ex * __uint_as_float(hv[u] & 0xffff0000u);
        }
    }
    for (; i < end; i += 2) {
        int idx = i + half;
        if (idx < end) {
            int s = adjsrc[idx];
            float e = as[s] + adh;
            e = e > 0.f ? e : 0.2f * e;
            float ex = __expf(e);
            ssum += ex;
            unsigned int hv = act ? *reinterpret_cast<const unsigned int*>(&h2b[(size_t)s * 48 + l * 2]) : 0u;
            acc0 += ex * __uint_as_float(hv << 16);
            acc1 += ex * __uint_as_float(hv & 0xffff0000u);
        }
    }
    acc0 += __shfl_xor(acc0, 32, 64);
    acc1 += __shfl_xor(acc1, 32, 64);
    ssum += __shfl_xor(ssum, 32, 64);
    if (half == 0 && act) {
        float inv = 1.f / (ssum + 1e-16f);
        float2 o;
        o.x = acc0 * inv + b[2 * l];
        o.y = acc1 * inv + b[2 * l + 1];
        *reinterpret_cast<float2*>(&out[(size_t)n * NCLS + 2 * l]) = o;
    }
}

extern "C" void kernel_launch(void* const* d_in, const int* in_sizes, int n_in,
                              void* d_out, int out_size, void* d_ws, size_t ws_size,
                              hipStream_t stream) {
    const float* x      = (const float*)d_in[0];
    const int*   ei     = (const int*)d_in[1];
    const float* W1     = (const float*)d_in[2];
    const float* a_src1 = (const float*)d_in[3];
    const float* a_dst1 = (const float*)d_in[4];
    const float* b1     = (const float*)d_in[5];
    const float* W2     = (const float*)d_in[6];
    const float* a_src2 = (const float*)d_in[7];
    const float* a_dst2 = (const float*)d_in[8];
    const float* b2     = (const float*)d_in[9];
    float* out = (float*)d_out;

    const int N = in_sizes[0] / IN_DIM;
    const int E = in_sizes[1] / 2;
    const int* src = ei;
    const int* dst = ei + E;

    char* ws = (char*)d_ws;
    size_t off = 0;
    auto alloc = [&](size_t bytes) {
        void* p = ws + off;
        off = (off + bytes + 255) & ~(size_t)255;
        return p;
    };
    int*   deg    = (int*)alloc((size_t)N * 4);
    int*   excl   = (int*)alloc((size_t)N * 4);
    int*   bsum   = (int*)alloc((size_t)256 * 4);
    int*   rank   = (int*)alloc((size_t)E * 4);
    int*   offs   = (int*)alloc((size_t)(N + 1) * 4);
    int*   adjsrc = (int*)alloc((size_t)E * 4);
    unsigned short* W1tb  = (unsigned short*)alloc((size_t)256 * 256 * 2);
    unsigned short* W2tb  = (unsigned short*)alloc((size_t)64 * 256 * 2);
    unsigned short* Aw    = (unsigned short*)alloc((size_t)16 * 256 * 2);
    unsigned short* h1b   = (unsigned short*)alloc((size_t)N * HIDDEN * 2);
    unsigned short* out1b = (unsigned short*)alloc((size_t)N * HIDDEN * 2);
    unsigned short* h2b   = (unsigned short*)alloc((size_t)N * 48 * 2);
    float* as1    = (float*)alloc((size_t)N * HEADS * 4);
    float* ad1    = (float*)alloc((size_t)N * HEADS * 4);
    float* as2    = (float*)alloc((size_t)N * 4);
    float* ad2    = (float*)alloc((size_t)N * 4);

    const int nb = (N + 1023) / 1024;
    const int nhist = (E + 255) / 256;

    hipMemsetAsync(deg, 0, (size_t)N * 4, stream);
    histprep_kernel<<<dim3(nhist + 320), dim3(256), 0, stream>>>(dst, deg, rank, E,
                                                                 W1, W2, a_src1, a_dst1, a_src2, a_dst2,
                                                                 W1tb, W2tb, Aw, nhist);
    scan_blocks_kernel<<<dim3(nb), dim3(1024), 0, stream>>>(deg, excl, bsum, N);
    add_base_kernel<<<dim3((N + 256) / 256), dim3(256), 0, stream>>>(excl, bsum, offs, N, nb);
    fill_kernel<<<dim3((E + 255) / 256), dim3(256), 0, stream>>>(src, dst, rank, offs, adjsrc, E);

    gemm1_mfma<<<dim3((N + 127) / 128), dim3(512), 0, stream>>>(x, W1tb, Aw, h1b, as1, ad1, N);
    agg1_kernel<<<dim3((N + 3) / 4), dim3(256), 0, stream>>>(h1b, as1, ad1, offs, adjsrc, b1, out1b, N);

    gemm2_mfma<<<dim3((N + 63) / 64), dim3(256), 0, stream>>>(out1b, W2tb, h2b, as2, ad2, N);
    agg2_kernel<<<dim3((N + 3) / 4), dim3(256), 0, stream>>>(h2b, as2, ad2, offs, adjsrc, b2, out, N);
}